// Round 2
// baseline (696.580 us; speedup 1.0000x reference)
//
#include <hip/hip_runtime.h>

typedef unsigned short ushort_t;
typedef __bf16 bf16x8 __attribute__((ext_vector_type(8)));
typedef float f32x4 __attribute__((ext_vector_type(4)));

#define SCALE_F 0.17677669529663687f  // 32^-0.5

__device__ __forceinline__ ushort_t f2bf(float f) {
  union { float f; unsigned u; } v; v.f = f;
  unsigned u = v.u;
  return (ushort_t)((u + 0x7FFFu + ((u >> 16) & 1u)) >> 16);  // RNE
}

// ---- prologue: transposed bf16 weights into workspace ----
__global__ __launch_bounds__(256, 1) void prep_weights(
    const float* __restrict__ wqkv, const float* __restrict__ wout,
    ushort_t* __restrict__ wqkvT, ushort_t* __restrict__ woutT) {
  int i = blockIdx.x * 256 + threadIdx.x;
  if (i < 768 * 256) {
    int n = i >> 8, k = i & 255;
    wqkvT[i] = f2bf(wqkv[k * 768 + n]);
  } else {
    int j = i - 768 * 256;
    int n = j >> 8, k = j & 255;
    woutT[j] = f2bf(wout[k * 256 + n]);
  }
}

// LDS map (bytes), all rows XOR-swizzled: byte ^= (row&7)<<4
//  [0,     32768) X   bf16 [64 tok][256 ch], stride 512  (persists all passes)
//  [32768, 40960) Qh  bf16 [64 tok][64 ch],  stride 128  } P overlays Qh+Kh
//  [40960, 49152) Kh  bf16 [64 key][64 ch],  stride 128  } (wave w at 32768+w*4096)
//  [49152, 57344) Vt  bf16 [64 ch][64 key],  stride 128
//  [57344, 65536) Op  bf16 [64 tok][64 ch],  stride 128  (per-pass O)
//  [65536, 67336) pe  f32  [2 heads][225]
//  [67336, 67592) lab i32  [64]
#define X_OFF   0
#define QH_OFF  32768
#define KH_OFF  40960
#define VT_OFF  49152
#define OP_OFF  57344
#define PE_OFF  65536
#define LAB_OFF 67336
#define SMEM_BYTES 67600

__device__ __forceinline__ char* lp(char* smem, int base, int row, int stride, int bc) {
  return smem + base + row * stride + (bc ^ ((row & 7) << 4));
}

__global__ __launch_bounds__(256, 2) void swin_attn(
    const float* __restrict__ x,
    const float* __restrict__ b_qkv,
    const float* __restrict__ b_out,
    const float* __restrict__ pos_enc,
    const ushort_t* __restrict__ wqkvT,
    const ushort_t* __restrict__ woutT,
    float* __restrict__ out) {
  __shared__ __attribute__((aligned(16))) char smem[SMEM_BYTES];
  int* lab = (int*)(smem + LAB_OFF);

  const int tid  = threadIdx.x;
  const int wid  = blockIdx.x;
  const int bb   = wid >> 6;
  const int w64  = wid & 63;
  const int wy   = w64 >> 3, wx = w64 & 7;
  const int wave = tid >> 6, lane = tid & 63;
  const int g    = lane >> 4, cc = lane & 15;

  // persistent out-projection accumulator: 16 queries (rows 16*wave..) x 256 ch
  f32x4 outacc[16];
  #pragma unroll
  for (int nt = 0; nt < 16; ++nt) outacc[nt] = (f32x4){0.f, 0.f, 0.f, 0.f};

  // ---------------- phase 0: shifted-window gather -> bf16 LDS ----------------
  {
    const float* xb = x + (size_t)bb * 4096 * 256;
    #pragma unroll
    for (int it = 0; it < 16; ++it) {
      int fi = tid + 256 * it;       // float4 index within 64 x 64 tile
      int r = fi >> 6, c4 = fi & 63;
      int hh = (8 * wy + (r >> 3) + 4) & 63;
      int ww = (8 * wx + (r & 7) + 4) & 63;
      const float4 v = ((const float4*)(xb + ((size_t)hh * 64 + ww) * 256))[c4];
      uint2 pk;
      pk.x = (unsigned)f2bf(v.x) | ((unsigned)f2bf(v.y) << 16);
      pk.y = (unsigned)f2bf(v.z) | ((unsigned)f2bf(v.w) << 16);
      *(uint2*)lp(smem, X_OFF, r, 512, 8 * c4) = pk;
    }
    if (tid < 64) {
      int py = 8 * wy + (tid >> 3), px = 8 * wx + (tid & 7);
      int ry = (py < 56) ? 0 : (py < 60 ? 1 : 2);
      int rx = (px < 56) ? 0 : (px < 60 ? 1 : 2);
      lab[tid] = ry * 3 + rx;
    }
  }
  __syncthreads();

  // ================= 4 passes over head pairs =================
  #pragma unroll 1
  for (int p = 0; p < 4; ++p) {
    // ---------- phase 1: QKV for heads 2p,2p+1 (12 16-col tiles / 4 waves) ----------
    {
      bf16x8 af[4][8];
      #pragma unroll
      for (int mt = 0; mt < 4; ++mt)
        #pragma unroll
        for (int ks = 0; ks < 8; ++ks)
          af[mt][ks] = *(const bf16x8*)lp(smem, X_OFF, 16 * mt + cc, 512, ks * 64 + g * 16);

      #pragma unroll 1
      for (int j = 0; j < 3; ++j) {
        int tt  = wave * 3 + j;
        int sel = tt >> 2, sub = tt & 3;          // sel: 0=Q 1=K 2=V
        int colg = sel * 256 + p * 64 + sub * 16 + cc;
        f32x4 acc[4];
        #pragma unroll
        for (int mt = 0; mt < 4; ++mt) acc[mt] = (f32x4){0.f, 0.f, 0.f, 0.f};
        #pragma unroll
        for (int ks = 0; ks < 8; ++ks) {
          bf16x8 bfr = *(const bf16x8*)&wqkvT[colg * 256 + ks * 32 + g * 8];
          #pragma unroll
          for (int mt = 0; mt < 4; ++mt)
            acc[mt] = __builtin_amdgcn_mfma_f32_16x16x32_bf16(af[mt][ks], bfr, acc[mt], 0, 0, 0);
        }
        float bias = b_qkv[colg];
        int cl = sub * 16 + cc;                   // pass-local channel 0..63
        #pragma unroll
        for (int mt = 0; mt < 4; ++mt)
          #pragma unroll
          for (int i = 0; i < 4; ++i) {
            int row = 16 * mt + 4 * g + i;        // token / key index
            ushort_t bv = f2bf(acc[mt][i] + bias);
            if (sel == 0)      *(ushort_t*)lp(smem, QH_OFF, row, 128, 2 * cl) = bv;
            else if (sel == 1) *(ushort_t*)lp(smem, KH_OFF, row, 128, 2 * cl) = bv;
            else               *(ushort_t*)lp(smem, VT_OFF, cl, 128, 2 * row) = bv;
          }
      }
      for (int i = tid; i < 450; i += 256)
        *(float*)(smem + PE_OFF + 4 * i) = pos_enc[p * 450 + i];
    }
    __syncthreads();  // (a) QKV + pe visible

    // ---------- phase 2: attention. wave -> head hl=wave>>1, query-half qh=wave&1 ----------
    {
      const int hl = wave >> 1, qh = wave & 1;
      bf16x8 qf[2], kf[4], vf[2][2];
      #pragma unroll
      for (int mt = 0; mt < 2; ++mt)
        qf[mt] = *(const bf16x8*)lp(smem, QH_OFF, 32 * qh + 16 * mt + cc, 128, hl * 64 + g * 16);
      #pragma unroll
      for (int nt = 0; nt < 4; ++nt)
        kf[nt] = *(const bf16x8*)lp(smem, KH_OFF, 16 * nt + cc, 128, hl * 64 + g * 16);
      #pragma unroll
      for (int nt = 0; nt < 2; ++nt)
        #pragma unroll
        for (int ks = 0; ks < 2; ++ks)
          vf[nt][ks] = *(const bf16x8*)lp(smem, VT_OFF, hl * 32 + 16 * nt + cc, 128, ks * 64 + g * 16);
      __syncthreads();  // (b) frag loads done -> P may overlay Qh/Kh

      f32x4 sacc[2][4];
      #pragma unroll
      for (int mt = 0; mt < 2; ++mt)
        #pragma unroll
        for (int nt = 0; nt < 4; ++nt)
          sacc[mt][nt] = (f32x4){0.f, 0.f, 0.f, 0.f};
      #pragma unroll
      for (int nt = 0; nt < 4; ++nt)
        #pragma unroll
        for (int mt = 0; mt < 2; ++mt)
          sacc[mt][nt] = __builtin_amdgcn_mfma_f32_16x16x32_bf16(qf[mt], kf[nt], sacc[mt][nt], 0, 0, 0);

      const float* peh = (const float*)(smem + PE_OFF) + hl * 225;
      char* Pw = smem + QH_OFF + wave * 4096;     // per-wave P [32 q][64 k]
      #pragma unroll
      for (int mt = 0; mt < 2; ++mt) {
        #pragma unroll
        for (int i = 0; i < 4; ++i) {
          int ql = 16 * mt + 4 * g + i;           // local query 0..31
          int q  = 32 * qh + ql;
          int y1 = q >> 3, x1 = q & 7;
          int lq = lab[q];
          float sv[4];
          #pragma unroll
          for (int nt = 0; nt < 4; ++nt) {
            int kk = 16 * nt + cc;
            float bias = peh[(y1 - (kk >> 3) + 7) * 15 + (x1 - (kk & 7) + 7)];
            float s = sacc[mt][nt][i] * SCALE_F + bias;
            sv[nt] = (lq != lab[kk]) ? -1e30f : s;
          }
          float m = fmaxf(fmaxf(sv[0], sv[1]), fmaxf(sv[2], sv[3]));
          m = fmaxf(m, __shfl_xor(m, 1));
          m = fmaxf(m, __shfl_xor(m, 2));
          m = fmaxf(m, __shfl_xor(m, 4));
          m = fmaxf(m, __shfl_xor(m, 8));
          float p0 = __expf(sv[0] - m), p1 = __expf(sv[1] - m);
          float p2 = __expf(sv[2] - m), p3 = __expf(sv[3] - m);
          float sum = p0 + p1 + p2 + p3;
          sum += __shfl_xor(sum, 1);
          sum += __shfl_xor(sum, 2);
          sum += __shfl_xor(sum, 4);
          sum += __shfl_xor(sum, 8);
          float rinv = 1.0f / sum;
          int sw = (ql & 7) << 4;
          *(ushort_t*)(Pw + ql * 128 + ((2 * (cc)      ) ^ sw)) = f2bf(p0 * rinv);
          *(ushort_t*)(Pw + ql * 128 + ((2 * (cc + 16) ) ^ sw)) = f2bf(p1 * rinv);
          *(ushort_t*)(Pw + ql * 128 + ((2 * (cc + 32) ) ^ sw)) = f2bf(p2 * rinv);
          *(ushort_t*)(Pw + ql * 128 + ((2 * (cc + 48) ) ^ sw)) = f2bf(p3 * rinv);
        }
      }
      asm volatile("s_waitcnt lgkmcnt(0)" ::: "memory");
      __builtin_amdgcn_sched_barrier(0);

      bf16x8 pf[2][2];
      #pragma unroll
      for (int mt = 0; mt < 2; ++mt)
        #pragma unroll
        for (int ks = 0; ks < 2; ++ks)
          pf[mt][ks] = *(const bf16x8*)(Pw + (16 * mt + cc) * 128 +
                          ((ks * 64 + g * 16) ^ (((16 * mt + cc) & 7) << 4)));
      f32x4 oacc[2][2];
      #pragma unroll
      for (int mt = 0; mt < 2; ++mt)
        #pragma unroll
        for (int nt = 0; nt < 2; ++nt)
          oacc[mt][nt] = (f32x4){0.f, 0.f, 0.f, 0.f};
      #pragma unroll
      for (int ks = 0; ks < 2; ++ks)
        #pragma unroll
        for (int nt = 0; nt < 2; ++nt)
          #pragma unroll
          for (int mt = 0; mt < 2; ++mt)
            oacc[mt][nt] = __builtin_amdgcn_mfma_f32_16x16x32_bf16(pf[mt][ks], vf[nt][ks], oacc[mt][nt], 0, 0, 0);

      #pragma unroll
      for (int mt = 0; mt < 2; ++mt)
        #pragma unroll
        for (int nt = 0; nt < 2; ++nt)
          #pragma unroll
          for (int i = 0; i < 4; ++i) {
            int row = 32 * qh + 16 * mt + 4 * g + i;
            *(ushort_t*)lp(smem, OP_OFF, row, 128, 2 * (hl * 32 + 16 * nt + cc)) =
                f2bf(oacc[mt][nt][i]);
          }
    }
    __syncthreads();  // (c) Op complete

    // ---------- phase 3: partial out-projection, K-slice = this pass's 64 channels ----------
    {
      bf16x8 ao[2];
      #pragma unroll
      for (int ks = 0; ks < 2; ++ks)
        ao[ks] = *(const bf16x8*)lp(smem, OP_OFF, 16 * wave + cc, 128, ks * 64 + g * 16);
      #pragma unroll
      for (int nt = 0; nt < 16; ++nt) {
        #pragma unroll
        for (int ks = 0; ks < 2; ++ks) {
          bf16x8 bfr = *(const bf16x8*)&woutT[(16 * nt + cc) * 256 + p * 64 + ks * 32 + g * 8];
          outacc[nt] = __builtin_amdgcn_mfma_f32_16x16x32_bf16(ao[ks], bfr, outacc[nt], 0, 0, 0);
        }
      }
    }
    // no barrier needed: next phase-1 touches Qh/Kh/Vt only; Op next written after (a)+(b)
  }

  // ---------------- epilogue: bias + reverse-shift scatter ----------------
  {
    #pragma unroll
    for (int nt = 0; nt < 16; ++nt) {
      float bo = b_out[16 * nt + cc];
      #pragma unroll
      for (int i = 0; i < 4; ++i) {
        int q  = 16 * wave + 4 * g + i;
        int hh = (8 * wy + (q >> 3) + 4) & 63;
        int ww = (8 * wx + (q & 7) + 4) & 63;
        out[(((size_t)bb * 4096) + hh * 64 + ww) * 256 + 16 * nt + cc] = outacc[nt][i] + bo;
      }
    }
  }
}

extern "C" void kernel_launch(void* const* d_in, const int* in_sizes, int n_in,
                              void* d_out, int out_size, void* d_ws, size_t ws_size,
                              hipStream_t stream) {
  const float* x       = (const float*)d_in[0];
  const float* w_qkv   = (const float*)d_in[1];
  const float* b_qkv   = (const float*)d_in[2];
  const float* w_out   = (const float*)d_in[3];
  const float* b_out   = (const float*)d_in[4];
  const float* pos_enc = (const float*)d_in[5];
  float* out = (float*)d_out;

  ushort_t* wqkvT = (ushort_t*)d_ws;            // 768*256 bf16
  ushort_t* woutT = wqkvT + 768 * 256;          // 256*256 bf16 (512 KB total)

  prep_weights<<<dim3((768 * 256 + 256 * 256) / 256), dim3(256), 0, stream>>>(
      w_qkv, w_out, wqkvT, woutT);
  swin_attn<<<dim3(2048), dim3(256), 0, stream>>>(
      x, b_qkv, b_out, pos_enc, wqkvT, woutT, out);
}

// Round 3
// 364.804 us; speedup vs baseline: 1.9095x; 1.9095x over previous
//
#include <hip/hip_runtime.h>

typedef unsigned short ushort_t;
typedef __bf16 bf16x8 __attribute__((ext_vector_type(8)));
typedef float f32x4 __attribute__((ext_vector_type(4)));

#define SCALE_F 0.17677669529663687f  // 32^-0.5

__device__ __forceinline__ ushort_t f2bf(float f) {
  union { float f; unsigned u; } v; v.f = f;
  unsigned u = v.u;
  return (ushort_t)((u + 0x7FFFu + ((u >> 16) & 1u)) >> 16);  // RNE
}
__device__ __forceinline__ float bf2f(ushort_t b) {
  union { unsigned u; float f; } v; v.u = ((unsigned)b) << 16;
  return v.f;
}

// ---- prep 1: transposed bf16 weights ----
__global__ __launch_bounds__(256, 1) void prep_weights(
    const float* __restrict__ wqkv, const float* __restrict__ wout,
    ushort_t* __restrict__ wqkvT, ushort_t* __restrict__ woutT) {
  int i = blockIdx.x * 256 + threadIdx.x;
  if (i < 768 * 256) {
    int n = i >> 8, k = i & 255;
    wqkvT[i] = f2bf(wqkv[k * 768 + n]);
  } else {
    int j = i - 768 * 256;
    int n = j >> 8, k = j & 255;
    woutT[j] = f2bf(wout[k * 256 + n]);
  }
}

// ---- prep 2: materialized rel-pos bias bias[h][q][k] bf16 (64 KB) ----
__global__ __launch_bounds__(256, 1) void prep_bias(
    const float* __restrict__ pos_enc, ushort_t* __restrict__ biasB) {
  int i = blockIdx.x * 256 + threadIdx.x;   // 8*64*64 = 32768
  int h = i >> 12, q = (i >> 6) & 63, k = i & 63;
  int y1 = q >> 3, x1 = q & 7, y2 = k >> 3, x2 = k & 7;
  biasB[i] = f2bf(pos_enc[h * 225 + (y1 - y2 + 7) * 15 + (x1 - x2 + 7)]);
}

// LDS (81920 B total -> 2 blocks/CU):
//  [0, 32768): X bf16 [64 tok][512B ch], swz ^((row&7)<<4)   -> O overlay (phase 3)
//  [32768 + w*12288, +12288): per-wave slab:
//     [0,4096):   Q_h [64 tok][64B],  swz ^((row&3)<<4)  } P [64q][128B] overlay,
//     [4096,8192): K_h [64 key][64B], swz ^((row&3)<<4)  }   swz ^((q&7)<<4)
//     [8192,12288): Vt_h [32 ch][128B tok], swz ^((ch&7)<<4)
__global__ __launch_bounds__(256, 2) void swin_attn(
    const float* __restrict__ x,
    const float* __restrict__ b_qkv,
    const float* __restrict__ b_out,
    const ushort_t* __restrict__ wqkvT,
    const ushort_t* __restrict__ woutT,
    const ushort_t* __restrict__ biasB,
    float* __restrict__ out) {
  __shared__ __attribute__((aligned(16))) char smem[81920];

  const int tid  = threadIdx.x;
  const int wid  = blockIdx.x;
  const int bb   = wid >> 6;
  const int w64  = wid & 63;
  const int wy   = w64 >> 3, wx = w64 & 7;
  const int wave = tid >> 6, lane = tid & 63;
  const int g    = lane >> 4, cc = lane & 15;

  // ---------------- phase 0: shifted-window gather -> X ----------------
  {
    const float* xb = x + (size_t)bb * 4096 * 256;
    #pragma unroll
    for (int it = 0; it < 16; ++it) {
      int fi = tid + 256 * it;
      int r = fi >> 6, c4 = fi & 63;
      int hh = (8 * wy + (r >> 3) + 4) & 63;
      int ww = (8 * wx + (r & 7) + 4) & 63;
      const float4 v = ((const float4*)(xb + ((size_t)hh * 64 + ww) * 256))[c4];
      uint2 pk;
      pk.x = (unsigned)f2bf(v.x) | ((unsigned)f2bf(v.y) << 16);
      pk.y = (unsigned)f2bf(v.z) | ((unsigned)f2bf(v.w) << 16);
      *(uint2*)(smem + r * 512 + ((8 * c4) ^ ((r & 7) << 4))) = pk;
    }
  }
  __syncthreads();

  char* slab = smem + 32768 + wave * 12288;
  // shift-mask key labels (per-thread, head-independent)
  int lk[4];
  {
    int rxk = (wx < 7) ? 0 : (((cc & 7) < 4) ? 1 : 2);
    #pragma unroll
    for (int nt = 0; nt < 4; ++nt) {
      int ky = 2 * nt + (cc >> 3);
      int ryk = (wy < 7) ? 0 : ((ky < 4) ? 1 : 2);
      lk[nt] = ryk * 3 + rxk;
    }
  }

  f32x4 oacc[2][4][2];
  #pragma unroll
  for (int a = 0; a < 2; ++a)
    #pragma unroll
    for (int b = 0; b < 4; ++b)
      #pragma unroll
      for (int c = 0; c < 2; ++c) oacc[a][b][c] = (f32x4){0.f, 0.f, 0.f, 0.f};

  // ================ per wave: 2 heads, fully private ================
  #pragma unroll
  for (int hh = 0; hh < 2; ++hh) {
    const int h = 2 * wave + hh;

    // ---- QKV GEMM for head h: 6 col-tiles (Q0 Q1 K0 K1 V0 V1), ks-outer ----
    f32x4 acc[6][4];
    #pragma unroll
    for (int u = 0; u < 6; ++u)
      #pragma unroll
      for (int mt = 0; mt < 4; ++mt) acc[u][mt] = (f32x4){0.f, 0.f, 0.f, 0.f};
    #pragma unroll
    for (int ks = 0; ks < 8; ++ks) {
      bf16x8 aks[4];
      #pragma unroll
      for (int mt = 0; mt < 4; ++mt) {
        int row = 16 * mt + cc;
        aks[mt] = *(const bf16x8*)(smem + row * 512 + ((64 * ks + 16 * g) ^ ((row & 7) << 4)));
      }
      #pragma unroll
      for (int u = 0; u < 6; ++u) {
        int colg = (u >> 1) * 256 + 32 * h + 16 * (u & 1) + cc;
        bf16x8 bfr = *(const bf16x8*)&wqkvT[colg * 256 + 32 * ks + 8 * g];
        #pragma unroll
        for (int mt = 0; mt < 4; ++mt)
          acc[u][mt] = __builtin_amdgcn_mfma_f32_16x16x32_bf16(aks[mt], bfr, acc[u][mt], 0, 0, 0);
      }
    }
    // slab-write epilogue (fence: prior head's P/V reads must land first)
    asm volatile("s_waitcnt lgkmcnt(0)" ::: "memory");
    __builtin_amdgcn_sched_barrier(0);
    #pragma unroll
    for (int u = 0; u < 6; ++u) {
      int sel = u >> 1;
      int chl = 16 * (u & 1) + cc;                       // head-local channel 0..31
      float bias = b_qkv[sel * 256 + 32 * h + chl];
      #pragma unroll
      for (int mt = 0; mt < 4; ++mt)
        #pragma unroll
        for (int i = 0; i < 4; ++i) {
          int row = 16 * mt + 4 * g + i;                 // token / key index
          ushort_t bv = f2bf(acc[u][mt][i] + bias);
          if (sel == 0)
            *(ushort_t*)(slab + row * 64 + ((2 * chl) ^ ((row & 3) << 4))) = bv;
          else if (sel == 1)
            *(ushort_t*)(slab + 4096 + row * 64 + ((2 * chl) ^ ((row & 3) << 4))) = bv;
          else
            *(ushort_t*)(slab + 8192 + chl * 128 + ((2 * row) ^ ((chl & 7) << 4))) = bv;
        }
    }
    asm volatile("s_waitcnt lgkmcnt(0)" ::: "memory");
    __builtin_amdgcn_sched_barrier(0);

    // ---- attention head h ----
    bf16x8 qf[4], kf[4], vf[2][2];
    #pragma unroll
    for (int mt = 0; mt < 4; ++mt) {
      int row = 16 * mt + cc;
      qf[mt] = *(const bf16x8*)(slab + row * 64 + ((16 * g) ^ ((row & 3) << 4)));
      kf[mt] = *(const bf16x8*)(slab + 4096 + row * 64 + ((16 * g) ^ ((row & 3) << 4)));
    }
    #pragma unroll
    for (int nt = 0; nt < 2; ++nt)
      #pragma unroll
      for (int ks = 0; ks < 2; ++ks) {
        int chl = 16 * nt + cc;
        vf[nt][ks] = *(const bf16x8*)(slab + 8192 + chl * 128 +
                                      ((64 * ks + 16 * g) ^ ((chl & 7) << 4)));
      }

    f32x4 sacc[4][4];
    #pragma unroll
    for (int mt = 0; mt < 4; ++mt)
      #pragma unroll
      for (int nt = 0; nt < 4; ++nt)
        sacc[mt][nt] = (f32x4){0.f, 0.f, 0.f, 0.f};
    #pragma unroll
    for (int nt = 0; nt < 4; ++nt)
      #pragma unroll
      for (int mt = 0; mt < 4; ++mt)
        sacc[mt][nt] = __builtin_amdgcn_mfma_f32_16x16x32_bf16(qf[mt], kf[nt], sacc[mt][nt], 0, 0, 0);

    // frag reads done before P overlays Q/K
    asm volatile("s_waitcnt lgkmcnt(0)" ::: "memory");
    __builtin_amdgcn_sched_barrier(0);

    const ushort_t* bh = biasB + h * 4096;
    #pragma unroll
    for (int mt = 0; mt < 4; ++mt) {
      #pragma unroll
      for (int i = 0; i < 4; ++i) {
        int q = 16 * mt + 4 * g + i;
        int qy = q >> 3, qx = q & 7;
        int lq = ((wy < 7) ? 0 : ((qy < 4) ? 1 : 2)) * 3 +
                 ((wx < 7) ? 0 : ((qx < 4) ? 1 : 2));
        float sv[4];
        #pragma unroll
        for (int nt = 0; nt < 4; ++nt) {
          int kk = 16 * nt + cc;
          float s = sacc[mt][nt][i] * SCALE_F + bf2f(bh[q * 64 + kk]);
          sv[nt] = (lq != lk[nt]) ? -1e30f : s;
        }
        float m = fmaxf(fmaxf(sv[0], sv[1]), fmaxf(sv[2], sv[3]));
        m = fmaxf(m, __shfl_xor(m, 1));
        m = fmaxf(m, __shfl_xor(m, 2));
        m = fmaxf(m, __shfl_xor(m, 4));
        m = fmaxf(m, __shfl_xor(m, 8));
        float p0 = __expf(sv[0] - m), p1 = __expf(sv[1] - m);
        float p2 = __expf(sv[2] - m), p3 = __expf(sv[3] - m);
        float sum = p0 + p1 + p2 + p3;
        sum += __shfl_xor(sum, 1);
        sum += __shfl_xor(sum, 2);
        sum += __shfl_xor(sum, 4);
        sum += __shfl_xor(sum, 8);
        float rinv = 1.0f / sum;
        int sw = (q & 7) << 4;
        *(ushort_t*)(slab + q * 128 + ((2 * cc)        ^ sw)) = f2bf(p0 * rinv);
        *(ushort_t*)(slab + q * 128 + ((2 * cc + 32)   ^ sw)) = f2bf(p1 * rinv);
        *(ushort_t*)(slab + q * 128 + ((2 * cc + 64)   ^ sw)) = f2bf(p2 * rinv);
        *(ushort_t*)(slab + q * 128 + ((2 * cc + 96)   ^ sw)) = f2bf(p3 * rinv);
      }
    }
    asm volatile("s_waitcnt lgkmcnt(0)" ::: "memory");
    __builtin_amdgcn_sched_barrier(0);

    bf16x8 pf[4][2];
    #pragma unroll
    for (int mt = 0; mt < 4; ++mt)
      #pragma unroll
      for (int ks = 0; ks < 2; ++ks) {
        int row = 16 * mt + cc;
        pf[mt][ks] = *(const bf16x8*)(slab + row * 128 +
                                      ((64 * ks + 16 * g) ^ ((row & 7) << 4)));
      }
    #pragma unroll
    for (int ks = 0; ks < 2; ++ks)
      #pragma unroll
      for (int nt = 0; nt < 2; ++nt)
        #pragma unroll
        for (int mt = 0; mt < 4; ++mt)
          oacc[hh][mt][nt] = __builtin_amdgcn_mfma_f32_16x16x32_bf16(
              pf[mt][ks], vf[nt][ks], oacc[hh][mt][nt], 0, 0, 0);
  }

  __syncthreads();  // all waves done with X + slabs -> O may overlay X region

  // ---- O write into [0,32768): O[64 tok][512B ch], same layout as X ----
  #pragma unroll
  for (int hh = 0; hh < 2; ++hh)
    #pragma unroll
    for (int mt = 0; mt < 4; ++mt)
      #pragma unroll
      for (int nt = 0; nt < 2; ++nt)
        #pragma unroll
        for (int i = 0; i < 4; ++i) {
          int tok = 16 * mt + 4 * g + i;
          int ch  = 64 * wave + 32 * hh + 16 * nt + cc;
          *(ushort_t*)(smem + tok * 512 + ((2 * ch) ^ ((tok & 7) << 4))) =
              f2bf(oacc[hh][mt][nt][i]);
        }
  __syncthreads();  // O complete

  // ---- out projection (ks-outer) + reverse-shift scatter ----
  {
    f32x4 pacc[4][4];  // [nt2][mt]
    #pragma unroll
    for (int a = 0; a < 4; ++a)
      #pragma unroll
      for (int b = 0; b < 4; ++b) pacc[a][b] = (f32x4){0.f, 0.f, 0.f, 0.f};
    #pragma unroll
    for (int ks = 0; ks < 8; ++ks) {
      bf16x8 aks[4];
      #pragma unroll
      for (int mt = 0; mt < 4; ++mt) {
        int row = 16 * mt + cc;
        aks[mt] = *(const bf16x8*)(smem + row * 512 + ((64 * ks + 16 * g) ^ ((row & 7) << 4)));
      }
      #pragma unroll
      for (int nt2 = 0; nt2 < 4; ++nt2) {
        int cs = 64 * wave + 16 * nt2;
        bf16x8 bfr = *(const bf16x8*)&woutT[(cs + cc) * 256 + 32 * ks + 8 * g];
        #pragma unroll
        for (int mt = 0; mt < 4; ++mt)
          pacc[nt2][mt] = __builtin_amdgcn_mfma_f32_16x16x32_bf16(aks[mt], bfr, pacc[nt2][mt], 0, 0, 0);
      }
    }
    #pragma unroll
    for (int nt2 = 0; nt2 < 4; ++nt2) {
      int cs = 64 * wave + 16 * nt2;
      float bo = b_out[cs + cc];
      #pragma unroll
      for (int mt = 0; mt < 4; ++mt)
        #pragma unroll
        for (int i = 0; i < 4; ++i) {
          int q  = 16 * mt + 4 * g + i;
          int hh = (8 * wy + (q >> 3) + 4) & 63;
          int ww = (8 * wx + (q & 7) + 4) & 63;
          out[(((size_t)bb * 4096) + hh * 64 + ww) * 256 + cs + cc] = pacc[nt2][mt][i] + bo;
        }
    }
  }
}

extern "C" void kernel_launch(void* const* d_in, const int* in_sizes, int n_in,
                              void* d_out, int out_size, void* d_ws, size_t ws_size,
                              hipStream_t stream) {
  const float* x       = (const float*)d_in[0];
  const float* w_qkv   = (const float*)d_in[1];
  const float* b_qkv   = (const float*)d_in[2];
  const float* w_out   = (const float*)d_in[3];
  const float* b_out   = (const float*)d_in[4];
  const float* pos_enc = (const float*)d_in[5];
  float* out = (float*)d_out;

  ushort_t* wqkvT = (ushort_t*)d_ws;            // 768*256
  ushort_t* woutT = wqkvT + 768 * 256;          // 256*256
  ushort_t* biasB = woutT + 256 * 256;          // 8*64*64  (total 576 KB)

  prep_weights<<<dim3((768 * 256 + 256 * 256) / 256), dim3(256), 0, stream>>>(
      w_qkv, w_out, wqkvT, woutT);
  prep_bias<<<dim3(128), dim3(256), 0, stream>>>(pos_enc, biasB);
  swin_attn<<<dim3(2048), dim3(256), 0, stream>>>(
      x, b_qkv, b_out, wqkvT, woutT, biasB, out);
}

// Round 4
// 204.663 us; speedup vs baseline: 3.4035x; 1.7825x over previous
//
#include <hip/hip_runtime.h>

typedef unsigned short ushort_t;
typedef __bf16 bf16x8 __attribute__((ext_vector_type(8)));
typedef float f32x4 __attribute__((ext_vector_type(4)));
typedef unsigned short u16x4 __attribute__((ext_vector_type(4)));

#define SCALE_F 0.17677669529663687f  // 32^-0.5
#define SWZ3(row) (((row) & 3) << 4)
#define SWZ7(row) (((row) & 7) << 4)

__device__ __forceinline__ ushort_t f2bf(float f) {
  union { float f; unsigned u; } v; v.f = f;
  unsigned u = v.u;
  return (ushort_t)((u + 0x7FFFu + ((u >> 16) & 1u)) >> 16);  // RNE
}
__device__ __forceinline__ float bf2f(ushort_t b) {
  union { unsigned u; float f; } v; v.u = ((unsigned)b) << 16;
  return v.f;
}
__device__ __forceinline__ void fence_lds() {
  asm volatile("s_waitcnt lgkmcnt(0)" ::: "memory");
  __builtin_amdgcn_sched_barrier(0);
}

// ---- prep 1: transposed bf16 weights ----
__global__ __launch_bounds__(256, 1) void prep_weights(
    const float* __restrict__ wqkv, const float* __restrict__ wout,
    ushort_t* __restrict__ wqkvT, ushort_t* __restrict__ woutT) {
  int i = blockIdx.x * 256 + threadIdx.x;
  if (i < 768 * 256) {
    int n = i >> 8, k = i & 255;
    wqkvT[i] = f2bf(wqkv[k * 768 + n]);
  } else {
    int j = i - 768 * 256;
    int n = j >> 8, k = j & 255;
    woutT[j] = f2bf(wout[k * 256 + n]);
  }
}

// ---- prep 2: materialized rel-pos bias bias[h][q][k] bf16 (64 KB) ----
__global__ __launch_bounds__(256, 1) void prep_bias(
    const float* __restrict__ pos_enc, ushort_t* __restrict__ biasB) {
  int i = blockIdx.x * 256 + threadIdx.x;   // 8*64*64 = 32768
  int h = i >> 12, q = (i >> 6) & 63, k = i & 63;
  int y1 = q >> 3, x1 = q & 7, y2 = k >> 3, x2 = k & 7;
  biasB[i] = f2bf(pos_enc[h * 225 + (y1 - y2 + 7) * 15 + (x1 - x2 + 7)]);
}

// LDS (81920 B -> 2 blocks/CU):
//  [0, 32768): X bf16 [64 tok][512B], swz ^((tok&7)<<4)  -> O overlay after barrier
//  [32768 + w*12288): per-wave slab:
//     [0,4096):    Q [64 tok][64B ch], swz ^((tok&3)<<4)  } P [64 q][128B k]
//     [4096,8192): K [64 key][64B ch], swz ^((key&3)<<4)  }   overlay, ^((q&7)<<4)
//     [8192,12288): Vt [32 ch][128B tok], swz ^((ch&7)<<4)
__global__ __launch_bounds__(256, 2) void swin_attn(
    const float* __restrict__ x,
    const float* __restrict__ b_qkv,
    const float* __restrict__ b_out,
    const ushort_t* __restrict__ wqkvT,
    const ushort_t* __restrict__ woutT,
    const ushort_t* __restrict__ biasB,
    float* __restrict__ out) {
  __shared__ __attribute__((aligned(16))) char smem[81920];

  const int tid  = threadIdx.x;
  const int wid  = blockIdx.x;
  const int bb   = wid >> 6;
  const int w64  = wid & 63;
  const int wy   = w64 >> 3, wx = w64 & 7;
  const int wave = tid >> 6, lane = tid & 63;
  const int g    = lane >> 4, cc = lane & 15;
  const bool maskY = (wy == 7), maskX = (wx == 7);
  const bool masked = maskY || maskX;

  // ---------------- phase 0: shifted-window gather -> X ----------------
  {
    const float* xb = x + (size_t)bb * 4096 * 256;
    #pragma unroll
    for (int it = 0; it < 16; ++it) {
      int fi = tid + 256 * it;
      int r = fi >> 6, c4 = fi & 63;
      int hh = (8 * wy + (r >> 3) + 4) & 63;
      int ww = (8 * wx + (r & 7) + 4) & 63;
      const float4 v = ((const float4*)(xb + ((size_t)hh * 64 + ww) * 256))[c4];
      uint2 pk;
      pk.x = (unsigned)f2bf(v.x) | ((unsigned)f2bf(v.y) << 16);
      pk.y = (unsigned)f2bf(v.z) | ((unsigned)f2bf(v.w) << 16);
      *(uint2*)(smem + r * 512 + ((8 * c4) ^ SWZ7(r))) = pk;
    }
  }
  __syncthreads();

  char* slab = smem + 32768 + wave * 12288;
  f32x4 oacc0[2][4], oacc1[2][4];
  float rinv0[4], rinv1[4];

  // ---- QKV for head h -> slab (Q,K swapped-orientation; V normal) ----
  auto qkv = [&](int h) {
    f32x4 aq[2][4], ak[2][4], av[2][4];
    #pragma unroll
    for (int c = 0; c < 2; ++c)
      #pragma unroll
      for (int t = 0; t < 4; ++t) {
        aq[c][t] = (f32x4){0.f,0.f,0.f,0.f};
        ak[c][t] = (f32x4){0.f,0.f,0.f,0.f};
        av[c][t] = (f32x4){0.f,0.f,0.f,0.f};
      }
    const ushort_t* wq = wqkvT + (size_t)(      32 * h) * 256;
    const ushort_t* wk = wqkvT + (size_t)(256 + 32 * h) * 256;
    const ushort_t* wv = wqkvT + (size_t)(512 + 32 * h) * 256;
    #pragma unroll
    for (int ks = 0; ks < 8; ++ks) {
      bf16x8 aks[4];
      #pragma unroll
      for (int t = 0; t < 4; ++t) {
        int row = 16 * t + cc;
        aks[t] = *(const bf16x8*)(smem + row * 512 + ((64 * ks + 16 * g) ^ SWZ7(row)));
      }
      #pragma unroll
      for (int c = 0; c < 2; ++c) {
        int roff = (16 * c + cc) * 256 + 32 * ks + 8 * g;
        bf16x8 fq = *(const bf16x8*)&wq[roff];
        bf16x8 fk = *(const bf16x8*)&wk[roff];
        bf16x8 fv = *(const bf16x8*)&wv[roff];
        #pragma unroll
        for (int t = 0; t < 4; ++t) {
          aq[c][t] = __builtin_amdgcn_mfma_f32_16x16x32_bf16(fq, aks[t], aq[c][t], 0, 0, 0);
          ak[c][t] = __builtin_amdgcn_mfma_f32_16x16x32_bf16(fk, aks[t], ak[c][t], 0, 0, 0);
          av[c][t] = __builtin_amdgcn_mfma_f32_16x16x32_bf16(aks[t], fv, av[c][t], 0, 0, 0);
        }
      }
    }
    fence_lds();  // prior slab reads (prev head pf/vf) must land before overwrite
    #pragma unroll
    for (int c = 0; c < 2; ++c) {
      float4 bq4 = *(const float4*)&b_qkv[      32 * h + 16 * c + 4 * g];
      float4 bk4 = *(const float4*)&b_qkv[256 + 32 * h + 16 * c + 4 * g];
      float bqa[4] = {bq4.x, bq4.y, bq4.z, bq4.w};
      float bka[4] = {bk4.x, bk4.y, bk4.z, bk4.w};
      #pragma unroll
      for (int t = 0; t < 4; ++t) {
        int tok = 16 * t + cc;
        u16x4 pq, pk;
        #pragma unroll
        for (int i = 0; i < 4; ++i) {
          pq[i] = f2bf((aq[c][t][i] + bqa[i]) * SCALE_F);
          pk[i] = f2bf(ak[c][t][i] + bka[i]);
        }
        *(u16x4*)(slab +        tok * 64 + ((32 * c + 8 * g) ^ SWZ3(tok))) = pq;
        *(u16x4*)(slab + 4096 + tok * 64 + ((32 * c + 8 * g) ^ SWZ3(tok))) = pk;
      }
      float bv = b_qkv[512 + 32 * h + 16 * c + cc];
      int ch = 16 * c + cc;
      #pragma unroll
      for (int t = 0; t < 4; ++t) {
        u16x4 pv;
        #pragma unroll
        for (int i = 0; i < 4; ++i) pv[i] = f2bf(av[c][t][i] + bv);
        *(u16x4*)(slab + 8192 + ch * 128 + ((32 * t + 8 * g) ^ SWZ7(ch))) = pv;
      }
    }
    fence_lds();  // slab writes visible before frag loads
  };

  // ---- attention for head h (Q,K,Vt in slab) -> oacc (=O^T tiles), rinv ----
  auto attn = [&](int h, f32x4 (*oacc)[4], float* rinv) {
    bf16x8 qf[4], kf[4], vf[2][2];
    #pragma unroll
    for (int t = 0; t < 4; ++t) {
      int row = 16 * t + cc;
      qf[t] = *(const bf16x8*)(slab +        row * 64 + ((16 * g) ^ SWZ3(row)));
      kf[t] = *(const bf16x8*)(slab + 4096 + row * 64 + ((16 * g) ^ SWZ3(row)));
    }
    #pragma unroll
    for (int c = 0; c < 2; ++c) {
      int ch = 16 * c + cc;
      #pragma unroll
      for (int ks = 0; ks < 2; ++ks)
        vf[c][ks] = *(const bf16x8*)(slab + 8192 + ch * 128 + ((64 * ks + 16 * g) ^ SWZ7(ch)));
    }
    fence_lds();  // frag loads done -> P may overlay Q/K

    f32x4 sacc[4][4];  // [key-tile nt][query-tile qt] : D[k][q] = S^T
    #pragma unroll
    for (int nt = 0; nt < 4; ++nt)
      #pragma unroll
      for (int qt = 0; qt < 4; ++qt) sacc[nt][qt] = (f32x4){0.f,0.f,0.f,0.f};
    #pragma unroll
    for (int qt = 0; qt < 4; ++qt)
      #pragma unroll
      for (int nt = 0; nt < 4; ++nt)
        sacc[nt][qt] = __builtin_amdgcn_mfma_f32_16x16x32_bf16(kf[nt], qf[qt], sacc[nt][qt], 0, 0, 0);

    const ushort_t* bh = biasB + h * 4096;
    const int rxq = maskX ? (((cc & 7) < 4) ? 1 : 2) : 0;  // qx = cc&7
    #pragma unroll
    for (int qt = 0; qt < 4; ++qt) {
      int q = 16 * qt + cc;
      float sv[4][4];
      float mx = -3.0e38f;
      #pragma unroll
      for (int nt = 0; nt < 4; ++nt) {
        u16x4 b4 = *(const u16x4*)&bh[q * 64 + 16 * nt + 4 * g];
        #pragma unroll
        for (int i = 0; i < 4; ++i)
          sv[nt][i] = sacc[nt][qt][i] + bf2f(b4[i]);
      }
      if (masked) {
        int qy = q >> 3;
        int lq = (maskY ? ((qy < 4) ? 1 : 2) : 0) * 3 + rxq;
        #pragma unroll
        for (int nt = 0; nt < 4; ++nt)
          #pragma unroll
          for (int i = 0; i < 4; ++i) {
            int k  = 16 * nt + 4 * g + i;
            int lk = (maskY ? (((k >> 3) < 4) ? 1 : 2) : 0) * 3 +
                     (maskX ? (((k & 7) < 4) ? 1 : 2) : 0);
            if (lq != lk) sv[nt][i] = -3.0e38f;
          }
      }
      #pragma unroll
      for (int nt = 0; nt < 4; ++nt)
        #pragma unroll
        for (int i = 0; i < 4; ++i) mx = fmaxf(mx, sv[nt][i]);
      mx = fmaxf(mx, __shfl_xor(mx, 16));
      mx = fmaxf(mx, __shfl_xor(mx, 32));
      float sum = 0.f;
      #pragma unroll
      for (int nt = 0; nt < 4; ++nt)
        #pragma unroll
        for (int i = 0; i < 4; ++i) {
          float e = __expf(sv[nt][i] - mx);
          sv[nt][i] = e;
          sum += e;
        }
      sum += __shfl_xor(sum, 16);
      sum += __shfl_xor(sum, 32);
      rinv[qt] = 1.0f / sum;
      #pragma unroll
      for (int nt = 0; nt < 4; ++nt) {
        u16x4 pp;
        #pragma unroll
        for (int i = 0; i < 4; ++i) pp[i] = f2bf(sv[nt][i]);
        *(u16x4*)(slab + q * 128 + ((32 * nt + 8 * g) ^ SWZ7(q))) = pp;
      }
    }
    fence_lds();  // P visible

    bf16x8 pf[4][2];
    #pragma unroll
    for (int qt = 0; qt < 4; ++qt) {
      int q = 16 * qt + cc;
      #pragma unroll
      for (int ks = 0; ks < 2; ++ks)
        pf[qt][ks] = *(const bf16x8*)(slab + q * 128 + ((64 * ks + 16 * g) ^ SWZ7(q)));
    }
    #pragma unroll
    for (int c = 0; c < 2; ++c)
      #pragma unroll
      for (int qt = 0; qt < 4; ++qt) oacc[c][qt] = (f32x4){0.f,0.f,0.f,0.f};
    #pragma unroll
    for (int ks = 0; ks < 2; ++ks)
      #pragma unroll
      for (int c = 0; c < 2; ++c)
        #pragma unroll
        for (int qt = 0; qt < 4; ++qt)
          oacc[c][qt] = __builtin_amdgcn_mfma_f32_16x16x32_bf16(vf[c][ks], pf[qt][ks], oacc[c][qt], 0, 0, 0);
  };

  // ---- O^T tiles -> X-overlay O[tok][512B ch] ----
  auto writeO = [&](f32x4 (*oacc)[4], float* rinv, int hh) {
    #pragma unroll
    for (int c = 0; c < 2; ++c)
      #pragma unroll
      for (int qt = 0; qt < 4; ++qt) {
        int q = 16 * qt + cc;
        u16x4 po;
        #pragma unroll
        for (int i = 0; i < 4; ++i) po[i] = f2bf(oacc[c][qt][i] * rinv[qt]);
        int cb = 2 * (64 * wave + 32 * hh + 16 * c + 4 * g);
        *(u16x4*)(smem + q * 512 + (cb ^ SWZ7(q))) = po;
      }
  };

  qkv(2 * wave);
  attn(2 * wave, oacc0, rinv0);
  qkv(2 * wave + 1);
  __syncthreads();                 // all waves done reading X
  writeO(oacc0, rinv0, 0);
  attn(2 * wave + 1, oacc1, rinv1);
  writeO(oacc1, rinv1, 1);
  __syncthreads();                 // O complete

  // ---- out projection (swapped: D[ch][tok]) + reverse-shift scatter ----
  {
    f32x4 pacc[4][4];  // [cht][tokt]
    #pragma unroll
    for (int c = 0; c < 4; ++c)
      #pragma unroll
      for (int t = 0; t < 4; ++t) pacc[c][t] = (f32x4){0.f,0.f,0.f,0.f};
    #pragma unroll
    for (int ks = 0; ks < 8; ++ks) {
      bf16x8 of[4];
      #pragma unroll
      for (int t = 0; t < 4; ++t) {
        int row = 16 * t + cc;
        of[t] = *(const bf16x8*)(smem + row * 512 + ((64 * ks + 16 * g) ^ SWZ7(row)));
      }
      #pragma unroll
      for (int c = 0; c < 4; ++c) {
        bf16x8 wf = *(const bf16x8*)&woutT[(size_t)(64 * wave + 16 * c + cc) * 256 + 32 * ks + 8 * g];
        #pragma unroll
        for (int t = 0; t < 4; ++t)
          pacc[c][t] = __builtin_amdgcn_mfma_f32_16x16x32_bf16(wf, of[t], pacc[c][t], 0, 0, 0);
      }
    }
    #pragma unroll
    for (int c = 0; c < 4; ++c) {
      int ch = 64 * wave + 16 * c + 4 * g;
      float4 bo4 = *(const float4*)&b_out[ch];
      #pragma unroll
      for (int t = 0; t < 4; ++t) {
        int q = 16 * t + cc;
        int hh2 = (8 * wy + (q >> 3) + 4) & 63;
        int ww2 = (8 * wx + (q & 7) + 4) & 63;
        float4 st;
        st.x = pacc[c][t][0] + bo4.x;
        st.y = pacc[c][t][1] + bo4.y;
        st.z = pacc[c][t][2] + bo4.z;
        st.w = pacc[c][t][3] + bo4.w;
        *(float4*)&out[(((size_t)bb * 4096) + hh2 * 64 + ww2) * 256 + ch] = st;
      }
    }
  }
}

extern "C" void kernel_launch(void* const* d_in, const int* in_sizes, int n_in,
                              void* d_out, int out_size, void* d_ws, size_t ws_size,
                              hipStream_t stream) {
  const float* x       = (const float*)d_in[0];
  const float* w_qkv   = (const float*)d_in[1];
  const float* b_qkv   = (const float*)d_in[2];
  const float* w_out   = (const float*)d_in[3];
  const float* b_out   = (const float*)d_in[4];
  const float* pos_enc = (const float*)d_in[5];
  float* out = (float*)d_out;

  ushort_t* wqkvT = (ushort_t*)d_ws;            // 768*256
  ushort_t* woutT = wqkvT + 768 * 256;          // 256*256
  ushort_t* biasB = woutT + 256 * 256;          // 8*64*64 (total 576 KB)

  prep_weights<<<dim3((768 * 256 + 256 * 256) / 256), dim3(256), 0, stream>>>(
      w_qkv, w_out, wqkvT, woutT);
  prep_bias<<<dim3(128), dim3(256), 0, stream>>>(pos_enc, biasB);
  swin_attn<<<dim3(2048), dim3(256), 0, stream>>>(
      x, b_qkv, b_out, wqkvT, woutT, biasB, out);
}

// Round 5
// 188.664 us; speedup vs baseline: 3.6922x; 1.0848x over previous
//
#include <hip/hip_runtime.h>

typedef __bf16 bf16_t;
typedef __bf16 bf16x4 __attribute__((ext_vector_type(4)));
typedef __bf16 bf16x8 __attribute__((ext_vector_type(8)));
typedef float f32x4 __attribute__((ext_vector_type(4)));

#define SCALE_LOG2E 0.25510803519787995f  // 32^-0.5 * log2(e)
#define LOG2E 1.4426950408889634f
#define SWZ(row) (((row) & 15) << 4)

__device__ __forceinline__ f32x4 mk4(float4 v) { return (f32x4){v.x, v.y, v.z, v.w}; }
__device__ __forceinline__ bf16x8 pack2(f32x4 a, f32x4 b) {
  bf16x4 lo = __builtin_convertvector(a, bf16x4);
  bf16x4 hi = __builtin_convertvector(b, bf16x4);
  return __builtin_shufflevector(lo, hi, 0, 1, 2, 3, 4, 5, 6, 7);
}

// ---- prep 1: transposed bf16 weights; Q/K head-rows permuted, Q pre-scaled ----
// wqkvT row n = s*256 + 32h + 16c + r  <- w_qkv col s*256 + 32h + 8*(r>>2) + 4c + (r&3)
__global__ __launch_bounds__(256, 1) void prep_weights(
    const float* __restrict__ wqkv, const float* __restrict__ wout,
    bf16_t* __restrict__ wqkvT, bf16_t* __restrict__ woutT) {
  int i = blockIdx.x * 256 + threadIdx.x;   // 1024*256
  int n = i >> 8, k = i & 255;
  if (n < 768) {
    int s = n >> 8, hl = n & 255;
    int src;
    if (s < 2) {
      int h = hl >> 5, w = hl & 31, c = (w >> 4) & 1, r = w & 15;
      src = 32 * h + 8 * (r >> 2) + 4 * c + (r & 3);
    } else {
      src = hl;
    }
    float v = wqkv[k * 768 + s * 256 + src];
    if (s == 0) v *= SCALE_LOG2E;
    wqkvT[n * 256 + k] = (bf16_t)v;
  } else {
    int m = n - 768;
    woutT[m * 256 + k] = (bf16_t)wout[k * 256 + m];
  }
}

// ---- prep 2: rel-pos bias, interleaved fragment order, log2e-scaled ----
// biasI[h][qt][nt][lane][i]
__global__ __launch_bounds__(256, 1) void prep_bias(
    const float* __restrict__ pos_enc, bf16_t* __restrict__ biasI) {
  int i = blockIdx.x * 256 + threadIdx.x;   // 8*4*4*64*4 = 32768
  int ii = i & 3, lane = (i >> 2) & 63, nt = (i >> 8) & 3, qt = (i >> 10) & 3, h = i >> 12;
  int g = lane >> 4, cc = lane & 15;
  int q = 32 * (qt >> 1) + 4 * (qt & 1) + 8 * (cc >> 2) + (cc & 3);
  int key = 32 * (nt >> 1) + 4 * (nt & 1) + 8 * g + ii;
  int qy = q >> 3, qx = q & 7, ky = key >> 3, kx = key & 7;
  biasI[i] = (bf16_t)(pos_enc[h * 225 + (qy - ky + 7) * 15 + (qx - kx + 7)] * LOG2E);
}

// LDS (65536 B -> 2 blocks/CU):
//  [0, 32768):     X bf16 [64 tok][512B ch], swz ^((tok&15)<<4)
//  [32768, 65536): O bf16 [64 tok][512B ch], swz ^((tok&15)<<4)
__global__ __launch_bounds__(256, 2) void swin_attn(
    const float* __restrict__ x,
    const float* __restrict__ b_qkv,
    const float* __restrict__ b_out,
    const bf16_t* __restrict__ wqkvT,
    const bf16_t* __restrict__ woutT,
    const bf16_t* __restrict__ biasI,
    float* __restrict__ out) {
  __shared__ __attribute__((aligned(16))) char smem[65536];
  char* Osm = smem + 32768;

  const int tid  = threadIdx.x;
  const int wid  = blockIdx.x;
  const int bb   = wid >> 6;
  const int w64  = wid & 63;
  const int wy   = w64 >> 3, wx = w64 & 7;
  const int wave = tid >> 6, lane = tid & 63;
  const int g    = lane >> 4, cc = lane & 15;
  const bool maskY = (wy == 7), maskX = (wx == 7);
  const int rb = 8 * (cc >> 2) + (cc & 3);   // interleaved row base per lane

  // ---------------- phase 0: shifted-window gather -> X (bf16) ----------------
  {
    const float* xb = x + (size_t)bb * 4096 * 256;
    #pragma unroll
    for (int it = 0; it < 16; ++it) {
      int fi = tid + 256 * it;
      int r = fi >> 6, c4 = fi & 63;
      int hh = (8 * wy + (r >> 3) + 4) & 63;
      int ww = (8 * wx + (r & 7) + 4) & 63;
      const float4 v = ((const float4*)(xb + ((size_t)hh * 64 + ww) * 256))[c4];
      bf16x4 pk = __builtin_convertvector(mk4(v), bf16x4);
      *(bf16x4*)(smem + r * 512 + ((8 * c4) ^ SWZ(r))) = pk;
    }
  }
  __syncthreads();

  // ================ per wave: 2 heads, fully in-register ================
  #pragma unroll
  for (int hh = 0; hh < 2; ++hh) {
    const int h = 2 * wave + hh;

    // ---- QKV GEMM: D rows permuted so outputs are MFMA fragments ----
    f32x4 aq[2][4], ak[2][4], av[4][2];
    #pragma unroll
    for (int c = 0; c < 2; ++c)
      #pragma unroll
      for (int t = 0; t < 4; ++t) {
        aq[c][t] = (f32x4){0.f, 0.f, 0.f, 0.f};
        ak[c][t] = (f32x4){0.f, 0.f, 0.f, 0.f};
        av[t][c] = (f32x4){0.f, 0.f, 0.f, 0.f};
      }
    const bf16_t* wq = wqkvT + (size_t)(      32 * h) * 256;
    const bf16_t* wk = wqkvT + (size_t)(256 + 32 * h) * 256;
    const bf16_t* wv = wqkvT + (size_t)(512 + 32 * h) * 256;
    #pragma unroll
    for (int ks = 0; ks < 8; ++ks) {
      bf16x8 aks[4];
      #pragma unroll
      for (int t = 0; t < 4; ++t) {
        int row = 32 * (t >> 1) + 4 * (t & 1) + rb;
        aks[t] = *(const bf16x8*)(smem + row * 512 + ((64 * ks + 16 * g) ^ SWZ(row)));
      }
      #pragma unroll
      for (int c = 0; c < 2; ++c) {
        int ro = (16 * c + cc) * 256 + 32 * ks + 8 * g;
        bf16x8 fq = *(const bf16x8*)&wq[ro];
        bf16x8 fk = *(const bf16x8*)&wk[ro];
        bf16x8 fv = *(const bf16x8*)&wv[ro];
        #pragma unroll
        for (int t = 0; t < 4; ++t) {
          aq[c][t] = __builtin_amdgcn_mfma_f32_16x16x32_bf16(fq, aks[t], aq[c][t], 0, 0, 0);
          ak[c][t] = __builtin_amdgcn_mfma_f32_16x16x32_bf16(fk, aks[t], ak[c][t], 0, 0, 0);
          av[t][c] = __builtin_amdgcn_mfma_f32_16x16x32_bf16(aks[t], fv, av[t][c], 0, 0, 0);
        }
      }
    }

    // ---- bias + pack into fragments (pure register ops) ----
    bf16x8 qp[4], kp[4], vp[2][2];
    {
      f32x4 bq0 = mk4(*(const float4*)&b_qkv[32 * h + 8 * g]) * SCALE_LOG2E;
      f32x4 bq1 = mk4(*(const float4*)&b_qkv[32 * h + 8 * g + 4]) * SCALE_LOG2E;
      f32x4 bk0 = mk4(*(const float4*)&b_qkv[256 + 32 * h + 8 * g]);
      f32x4 bk1 = mk4(*(const float4*)&b_qkv[256 + 32 * h + 8 * g + 4]);
      #pragma unroll
      for (int t = 0; t < 4; ++t) {
        qp[t] = pack2(aq[0][t] + bq0, aq[1][t] + bq1);
        kp[t] = pack2(ak[0][t] + bk0, ak[1][t] + bk1);
      }
      #pragma unroll
      for (int c = 0; c < 2; ++c) {
        float bv = b_qkv[512 + 32 * h + 16 * c + cc];
        f32x4 bv4 = (f32x4){bv, bv, bv, bv};
        #pragma unroll
        for (int ks = 0; ks < 2; ++ks)
          vp[c][ks] = pack2(av[2 * ks][c] + bv4, av[2 * ks + 1][c] + bv4);
      }
    }

    // ---- S^T = K·Q^T (rows=keys interleaved, cols=q interleaved) ----
    f32x4 sacc[4][4];
    #pragma unroll
    for (int nt = 0; nt < 4; ++nt)
      #pragma unroll
      for (int qt = 0; qt < 4; ++qt) sacc[nt][qt] = (f32x4){0.f, 0.f, 0.f, 0.f};
    #pragma unroll
    for (int qt = 0; qt < 4; ++qt)
      #pragma unroll
      for (int nt = 0; nt < 4; ++nt)
        sacc[nt][qt] = __builtin_amdgcn_mfma_f32_16x16x32_bf16(kp[nt], qp[qt], sacc[nt][qt], 0, 0, 0);

    // ---- softmax (exp2-domain; mask is tile-uniform) + pack P ----
    bf16x8 pf[4][2];
    const bf16_t* bI = biasI + h * 4096 + lane * 4;
    #pragma unroll
    for (int qt = 0; qt < 4; ++qt) {
      f32x4 sv[4];
      #pragma unroll
      for (int nt = 0; nt < 4; ++nt) {
        bool dead = (maskY && ((qt < 2) != (nt < 2))) || (maskX && ((qt & 1) != (nt & 1)));
        if (dead) {
          sv[nt] = (f32x4){-3.0e38f, -3.0e38f, -3.0e38f, -3.0e38f};
        } else {
          bf16x4 bb = *(const bf16x4*)&bI[(qt * 4 + nt) * 256];
          sv[nt] = sacc[nt][qt] + __builtin_convertvector(bb, f32x4);
        }
      }
      float mx = -3.0e38f;
      #pragma unroll
      for (int nt = 0; nt < 4; ++nt)
        #pragma unroll
        for (int i = 0; i < 4; ++i) mx = fmaxf(mx, sv[nt][i]);
      mx = fmaxf(mx, __shfl_xor(mx, 16));
      mx = fmaxf(mx, __shfl_xor(mx, 32));
      float sum = 0.f;
      #pragma unroll
      for (int nt = 0; nt < 4; ++nt)
        #pragma unroll
        for (int i = 0; i < 4; ++i) {
          float e = exp2f(sv[nt][i] - mx);
          sv[nt][i] = e;
          sum += e;
        }
      sum += __shfl_xor(sum, 16);
      sum += __shfl_xor(sum, 32);
      float rinv = 1.0f / sum;
      #pragma unroll
      for (int nt = 0; nt < 4; ++nt) sv[nt] *= rinv;
      pf[qt][0] = pack2(sv[0], sv[1]);
      pf[qt][1] = pack2(sv[2], sv[3]);
    }

    // ---- O^T = V^T·P^T ----
    f32x4 oacc[2][4];
    #pragma unroll
    for (int c = 0; c < 2; ++c)
      #pragma unroll
      for (int qt = 0; qt < 4; ++qt) oacc[c][qt] = (f32x4){0.f, 0.f, 0.f, 0.f};
    #pragma unroll
    for (int ks = 0; ks < 2; ++ks)
      #pragma unroll
      for (int c = 0; c < 2; ++c)
        #pragma unroll
        for (int qt = 0; qt < 4; ++qt)
          oacc[c][qt] = __builtin_amdgcn_mfma_f32_16x16x32_bf16(vp[c][ks], pf[qt][ks], oacc[c][qt], 0, 0, 0);

    // ---- write O (own channel columns; no sync needed until proj) ----
    #pragma unroll
    for (int c = 0; c < 2; ++c)
      #pragma unroll
      for (int qt = 0; qt < 4; ++qt) {
        int tok = 32 * (qt >> 1) + 4 * (qt & 1) + rb;
        bf16x4 ob = __builtin_convertvector(oacc[c][qt], bf16x4);
        *(bf16x4*)(Osm + tok * 512 +
                   ((2 * (64 * wave + 32 * hh + 16 * c + 4 * g)) ^ SWZ(tok))) = ob;
      }
  }
  __syncthreads();  // all O written

  // ---- out projection D = W_out·O^T + reverse-shift scatter ----
  {
    f32x4 pacc[4][4];  // [c2][t]
    #pragma unroll
    for (int c = 0; c < 4; ++c)
      #pragma unroll
      for (int t = 0; t < 4; ++t) pacc[c][t] = (f32x4){0.f, 0.f, 0.f, 0.f};
    #pragma unroll
    for (int ks = 0; ks < 8; ++ks) {
      bf16x8 of[4];
      #pragma unroll
      for (int t = 0; t < 4; ++t) {
        int row = 16 * t + cc;
        of[t] = *(const bf16x8*)(Osm + row * 512 + ((64 * ks + 16 * g) ^ SWZ(row)));
      }
      #pragma unroll
      for (int c2 = 0; c2 < 4; ++c2) {
        bf16x8 wf = *(const bf16x8*)&woutT[(size_t)(64 * wave + 16 * c2 + cc) * 256 + 32 * ks + 8 * g];
        #pragma unroll
        for (int t = 0; t < 4; ++t)
          pacc[c2][t] = __builtin_amdgcn_mfma_f32_16x16x32_bf16(wf, of[t], pacc[c2][t], 0, 0, 0);
      }
    }
    #pragma unroll
    for (int c2 = 0; c2 < 4; ++c2) {
      int ch = 64 * wave + 16 * c2 + 4 * g;
      float4 bo4 = *(const float4*)&b_out[ch];
      #pragma unroll
      for (int t = 0; t < 4; ++t) {
        int q = 16 * t + cc;
        int hh2 = (8 * wy + (q >> 3) + 4) & 63;
        int ww2 = (8 * wx + (q & 7) + 4) & 63;
        float4 st;
        st.x = pacc[c2][t][0] + bo4.x;
        st.y = pacc[c2][t][1] + bo4.y;
        st.z = pacc[c2][t][2] + bo4.z;
        st.w = pacc[c2][t][3] + bo4.w;
        *(float4*)&out[(((size_t)bb * 4096) + hh2 * 64 + ww2) * 256 + ch] = st;
      }
    }
  }
}

extern "C" void kernel_launch(void* const* d_in, const int* in_sizes, int n_in,
                              void* d_out, int out_size, void* d_ws, size_t ws_size,
                              hipStream_t stream) {
  const float* x       = (const float*)d_in[0];
  const float* w_qkv   = (const float*)d_in[1];
  const float* b_qkv   = (const float*)d_in[2];
  const float* w_out   = (const float*)d_in[3];
  const float* b_out   = (const float*)d_in[4];
  const float* pos_enc = (const float*)d_in[5];
  float* out = (float*)d_out;

  bf16_t* wqkvT = (bf16_t*)d_ws;          // 768*256
  bf16_t* woutT = wqkvT + 768 * 256;      // 256*256
  bf16_t* biasI = woutT + 256 * 256;      // 32768

  prep_weights<<<dim3(1024), dim3(256), 0, stream>>>(w_qkv, w_out, wqkvT, woutT);
  prep_bias<<<dim3(128), dim3(256), 0, stream>>>(pos_enc, biasI);
  swin_attn<<<dim3(2048), dim3(256), 0, stream>>>(
      x, b_qkv, b_out, wqkvT, woutT, biasI, out);
}